// Round 6
// baseline (420.382 us; speedup 1.0000x reference)
//
#include <hip/hip_runtime.h>

// GCN rank-1 collapse + 2-level counting-sort partition (R12).
// R11 post-mortem: 4x MLP on wh = null (61us pinned, VALUBusy down) ->
// wh is L2 random-gather THROUGHPUT-bound: 10M gathers x 64B line = 640MB
// of L2 line traffic ~= 11.7 TB/s aggregate = random-access L2 ceiling.
// R12: second-level partition by src-block -> 62x62 cells; wh2d stages the
// 32KB table slice per src-block into LDS and gathers from LDS (ds_read
// ~5.8cyc/wave) -> L2 gather traffic becomes ~127MB of STREAMED slice
// loads. srcP+deghist machinery deleted: deg_in/deg_out both computed from
// the 2D cells (u16 partials aliased over dead level-1 dstP). req2D ~99.7MB
// fits whenever the old 102.6MB layout fit; 1D (R11) path kept as fallback.

#define TB 256
#define DTB 512
#define STB 512
#define BSH 13
#define BNODES 8192
#define MAXNB 64
#define SCH 4096
#define SCH4 (SCH / 4)
#define SCH2 4096
#define EPT 8
#define CSTR 16
#define GLG 4
#define GNUM 16
#define INVB 0xFFFFFFFFu

typedef __attribute__((ext_vector_type(4))) int int4v;
typedef __attribute__((ext_vector_type(4))) unsigned uint4v;
typedef __attribute__((ext_vector_type(2))) unsigned uint2v;
typedef __attribute__((ext_vector_type(4))) float float4v;

__global__ void init_kernel(unsigned* __restrict__ curD, unsigned* __restrict__ curS,
                            unsigned* __restrict__ curC, float* __restrict__ Xsum,
                            int NB, unsigned CAP, int cells, unsigned CAP2, int G) {
    int i = blockIdx.x * TB + threadIdx.x;
    if (i < NB) curD[i * CSTR] = (unsigned)i * CAP;
    if (curS && i < NB) curS[i * CSTR] = (unsigned)i * CAP;
    if (curC && i < cells) curC[i * CSTR] = (unsigned)i * CAP2;
    if (i < G) Xsum[i] = 0.0f;
}

// Level-1: partition edges by dst-block. srcP==nullptr -> 2D mode (no S side).
__global__ void scatter_sort_kernel(const int* __restrict__ src, const int* __restrict__ dst,
                                    unsigned* __restrict__ curD, unsigned* __restrict__ curS,
                                    unsigned* __restrict__ dstP, unsigned short* __restrict__ srcP,
                                    int NB, int E, int blk0) {
    __shared__ unsigned cntD[MAXNB], cntS[MAXNB];
    __shared__ unsigned deltaD[MAXNB], deltaS[MAXNB];
    __shared__ unsigned totD_s, totS_s;
    __shared__ unsigned payD[SCH];
    __shared__ unsigned short valS[SCH];
    __shared__ unsigned char mapD[SCH], mapS[SCH];

    int tid = threadIdx.x;
    if (tid < MAXNB) { cntD[tid] = 0u; cntS[tid] = 0u; }
    __syncthreads();

    unsigned sA[EPT], dA[EPT], bD[EPT], bS[EPT];
    int blk = blockIdx.x + blk0;
#pragma unroll
    for (int v = 0; v < 2; ++v) {
        int q = blk * SCH4 + v * STB + tid;
        int be = q * 4;
        if (be + 3 < E) {
            int4v s4 = __builtin_nontemporal_load((const int4v*)src + q);
            int4v d4 = __builtin_nontemporal_load((const int4v*)dst + q);
#pragma unroll
            for (int k = 0; k < 4; ++k) {
                sA[v*4+k] = (unsigned)s4[k];
                dA[v*4+k] = (unsigned)d4[k];
                bD[v*4+k] = dA[v*4+k] >> BSH;
                bS[v*4+k] = sA[v*4+k] >> BSH;
            }
        } else {
#pragma unroll
            for (int k = 0; k < 4; ++k) {
                int j = be + k;
                if (j < E) {
                    sA[v*4+k] = (unsigned)src[j];
                    dA[v*4+k] = (unsigned)dst[j];
                    bD[v*4+k] = dA[v*4+k] >> BSH;
                    bS[v*4+k] = sA[v*4+k] >> BSH;
                } else {
                    bD[v*4+k] = INVB; bS[v*4+k] = INVB;
                    sA[v*4+k] = 0u; dA[v*4+k] = 0u;
                }
            }
        }
    }

#pragma unroll
    for (int k = 0; k < EPT; ++k) {
        if (bD[k] != INVB) {
            atomicAdd(&cntD[bD[k]], 1u);
            if (srcP) atomicAdd(&cntS[bS[k]], 1u);
        }
    }
    __syncthreads();

    int wv = tid >> 6, ln = tid & 63;
    if (wv == 0) {
        unsigned x = (ln < NB) ? cntD[ln] : 0u;
        unsigned inc = x;
#pragma unroll
        for (int o = 1; o < 64; o <<= 1) {
            unsigned y = __shfl_up(inc, o, 64);
            if (ln >= o) inc += y;
        }
        unsigned exc = inc - x;
        if (ln < NB) {
            unsigned gb = atomicAdd(&curD[ln * CSTR], x);
            deltaD[ln] = gb - exc;
            cntD[ln] = exc;
        }
        if (ln == 63) totD_s = inc;
    } else if (wv == 1 && srcP) {
        unsigned x = (ln < NB) ? cntS[ln] : 0u;
        unsigned inc = x;
#pragma unroll
        for (int o = 1; o < 64; o <<= 1) {
            unsigned y = __shfl_up(inc, o, 64);
            if (ln >= o) inc += y;
        }
        unsigned exc = inc - x;
        if (ln < NB) {
            unsigned gb = atomicAdd(&curS[ln * CSTR], x);
            deltaS[ln] = gb - exc;
            cntS[ln] = exc;
        }
        if (ln == 63) totS_s = inc;
    }
    __syncthreads();

#pragma unroll
    for (int k = 0; k < EPT; ++k) {
        if (bD[k] != INVB) {
            unsigned p = atomicAdd(&cntD[bD[k]], 1u);
            payD[p] = ((dA[k] & (BNODES - 1)) << 19) | sA[k];
            mapD[p] = (unsigned char)bD[k];
            if (srcP) {
                unsigned p2 = atomicAdd(&cntS[bS[k]], 1u);
                valS[p2] = (unsigned short)(sA[k] & (BNODES - 1));
                mapS[p2] = (unsigned char)bS[k];
            }
        }
    }
    __syncthreads();

    unsigned tD = totD_s;
    for (unsigned i = tid; i < tD; i += STB) {
        unsigned b = mapD[i];
        dstP[deltaD[b] + i] = payD[i];
    }
    if (srcP) {
        unsigned tS = totS_s;
        for (unsigned i = tid; i < tS; i += STB) {
            unsigned b = mapS[i];
            srcP[deltaS[b] + i] = valS[i];
        }
    }
}

// Level-2: split each dst-bucket by src-block into cells.
// Payload out: (dst_local:13 << 13) | src_local:13.
__global__ void subsort_kernel(const unsigned* __restrict__ dstP, const unsigned* __restrict__ curD,
                               unsigned* __restrict__ curC, unsigned* __restrict__ dstP2,
                               unsigned CAP, unsigned CAP2, int NB, int MAXCH) {
    __shared__ unsigned cnt2[MAXNB], delta2[MAXNB];
    __shared__ unsigned tot_s;
    __shared__ unsigned pay[SCH2];
    __shared__ unsigned char map2[SCH2];

    int db = blockIdx.x / MAXCH, c = blockIdx.x % MAXCH;
    unsigned s = (unsigned)db * CAP + (unsigned)c * SCH2;
    unsigned e = curD[db * CSTR];            // absolute end of db region
    if (s >= e) return;                      // uniform early-out
    unsigned n = e - s; if (n > SCH2) n = SCH2;

    int tid = threadIdx.x;
    if (tid < MAXNB) cnt2[tid] = 0u;
    __syncthreads();

    unsigned pl[EPT], bk[EPT];
#pragma unroll
    for (int v = 0; v < 2; ++v) {
        unsigned q = (unsigned)(v * STB + tid);
        unsigned base = q * 4u;
        if (base + 3u < n) {
            uint4v p4 = *((const uint4v*)(dstP + s) + q);
#pragma unroll
            for (int k = 0; k < 4; ++k) {
                pl[v*4+k] = p4[k];
                bk[v*4+k] = (p4[k] & 0x7FFFFu) >> BSH;
            }
        } else {
#pragma unroll
            for (int k = 0; k < 4; ++k) {
                unsigned j = base + (unsigned)k;
                if (j < n) {
                    pl[v*4+k] = dstP[s + j];
                    bk[v*4+k] = (pl[v*4+k] & 0x7FFFFu) >> BSH;
                } else { bk[v*4+k] = INVB; pl[v*4+k] = 0u; }
            }
        }
    }

#pragma unroll
    for (int k = 0; k < EPT; ++k)
        if (bk[k] != INVB) atomicAdd(&cnt2[bk[k]], 1u);
    __syncthreads();

    if (tid < 64) {
        int ln = tid;
        unsigned x = cnt2[ln];
        unsigned inc = x;
#pragma unroll
        for (int o = 1; o < 64; o <<= 1) {
            unsigned y = __shfl_up(inc, o, 64);
            if (ln >= o) inc += y;
        }
        unsigned exc = inc - x;
        if (ln < NB) {
            unsigned gb = atomicAdd(&curC[((unsigned)db * NB + ln) * CSTR], x);
            delta2[ln] = gb - exc;
            cnt2[ln] = exc;
        }
        if (ln == 63) tot_s = inc;
    }
    __syncthreads();

#pragma unroll
    for (int k = 0; k < EPT; ++k) {
        if (bk[k] != INVB) {
            unsigned p = atomicAdd(&cnt2[bk[k]], 1u);
            pay[p] = ((pl[k] >> 19) << BSH) | (pl[k] & (BNODES - 1));
            map2[p] = (unsigned char)bk[k];
        }
    }
    __syncthreads();

    unsigned tot = tot_s;
    for (unsigned i = tid; i < tot; i += STB) {
        unsigned b = map2[i];
        dstP2[delta2[b] + i] = pay[i];
    }
}

// deg_in partials: block (db, g) histograms dst_local over cells (db, sb in group).
__global__ void degin2_kernel(const unsigned* __restrict__ dstP2, const unsigned* __restrict__ curC,
                              unsigned CAP2, unsigned short* __restrict__ pDegIn, int NB, int GS) {
    __shared__ unsigned h[BNODES];
    {
        uint4v* hv = (uint4v*)h;
        for (int t = threadIdx.x; t < BNODES / 4; t += DTB) hv[t] = (uint4v)0u;
    }
    __syncthreads();
    int db = blockIdx.x >> GLG, g = blockIdx.x & (GNUM - 1);
    int sbEnd = (g + 1) * GS; if (sbEnd > NB) sbEnd = NB;
    for (int sb = g * GS; sb < sbEnd; ++sb) {
        unsigned cell = (unsigned)(db * NB + sb);
        unsigned lo = cell * CAP2;
        unsigned hi = curC[cell * CSTR];
        for (unsigned i = lo + threadIdx.x; i < hi; i += DTB)
            atomicAdd(&h[dstP2[i] >> BSH], 1u);
    }
    __syncthreads();
    unsigned short* row = pDegIn + (size_t)blockIdx.x * BNODES;
    for (int t = threadIdx.x; t < BNODES; t += DTB) row[t] = (unsigned short)h[t];
}

// deg_out partials: block (sb, g) histograms src_local over cells (db in group, sb).
__global__ void degout2_kernel(const unsigned* __restrict__ dstP2, const unsigned* __restrict__ curC,
                               unsigned CAP2, unsigned short* __restrict__ pDegOut, int NB, int GS) {
    __shared__ unsigned h[BNODES];
    {
        uint4v* hv = (uint4v*)h;
        for (int t = threadIdx.x; t < BNODES / 4; t += DTB) hv[t] = (uint4v)0u;
    }
    __syncthreads();
    int sb = blockIdx.x >> GLG, g = blockIdx.x & (GNUM - 1);
    int dbEnd = (g + 1) * GS; if (dbEnd > NB) dbEnd = NB;
    for (int db = g * GS; db < dbEnd; ++db) {
        unsigned cell = (unsigned)(db * NB + sb);
        unsigned lo = cell * CAP2;
        unsigned hi = curC[cell * CSTR];
        for (unsigned i = lo + threadIdx.x; i < hi; i += DTB)
            atomicAdd(&h[dstP2[i] & (BNODES - 1)], 1u);
    }
    __syncthreads();
    unsigned short* row = pDegOut + (size_t)blockIdx.x * BNODES;
    for (int t = threadIdx.x; t < BNODES; t += DTB) row[t] = (unsigned short)h[t];
}

__global__ void prep2_kernel(const unsigned short* __restrict__ pDegIn,
                             const unsigned short* __restrict__ pDegOut,
                             float* __restrict__ pio, float* __restrict__ h0s,
                             float* __restrict__ isiA, int Npad) {
    int i = blockIdx.x * TB + threadIdx.x;
    if (i >= Npad) return;
    int b = i >> BSH, l = i & (BNODES - 1);
    unsigned din_u = 0, dout_u = 0;
    for (int g = 0; g < GNUM; ++g) {
        din_u  += __builtin_nontemporal_load(&pDegIn [(size_t)(b * GNUM + g) * BNODES + l]);
        dout_u += __builtin_nontemporal_load(&pDegOut[(size_t)(b * GNUM + g) * BNODES + l]);
    }
    float din = (float)din_u, dout = (float)dout_u;
    float a  = 1.0f / sqrtf(fmaxf(din, 1.0f));
    float bo = 1.0f / sqrtf(fmaxf(dout, 1.0f));
    pio[i]  = a * bo;
    h0s[i]  = din * bo;
    isiA[i] = a;
}

// 2D weighted histogram: per sb, stage 32KB table slice into LDS, gather from LDS.
template <int LAST>
__global__ void wh2d_kernel(const unsigned* __restrict__ dstP2, const unsigned* __restrict__ curC,
                            unsigned CAP2, const float* __restrict__ table,
                            float* __restrict__ pOut, int NB, int GS) {
    __shared__ float h[BNODES];
    __shared__ float slice[BNODES];
    {
        float4v* hv = (float4v*)h;
        for (int t = threadIdx.x; t < BNODES / 4; t += DTB) hv[t] = (float4v)0.0f;
    }
    int db = blockIdx.x >> GLG, g = blockIdx.x & (GNUM - 1);
    int sbEnd = (g + 1) * GS; if (sbEnd > NB) sbEnd = NB;
    for (int sb = g * GS; sb < sbEnd; ++sb) {
        __syncthreads();   // prior iter's slice readers done (also covers h zero)
        {
            const float4v* tp = (const float4v*)(table + ((size_t)sb << BSH));
            float4v* sp = (float4v*)slice;
            for (int t = threadIdx.x; t < BNODES / 4; t += DTB) sp[t] = tp[t];
        }
        __syncthreads();
        unsigned cell = (unsigned)(db * NB + sb);
        unsigned lo = cell * CAP2;       // CAP2 is 128-aligned -> lo 16B-aligned
        unsigned hi = curC[cell * CSTR];
        unsigned i1 = hi & ~3u;
        const uint4v* qp = (const uint4v*)(dstP2 + lo);
        for (unsigned q = threadIdx.x; q < (i1 - lo) / 4u; q += DTB) {
            uint4v e4 = LAST ? __builtin_nontemporal_load(qp + q) : qp[q];
            float t0 = slice[e4.x & (BNODES - 1)];
            float t1 = slice[e4.y & (BNODES - 1)];
            float t2 = slice[e4.z & (BNODES - 1)];
            float t3 = slice[e4.w & (BNODES - 1)];
            atomicAdd(&h[e4.x >> BSH], t0);
            atomicAdd(&h[e4.y >> BSH], t1);
            atomicAdd(&h[e4.z >> BSH], t2);
            atomicAdd(&h[e4.w >> BSH], t3);
        }
        if (threadIdx.x < hi - i1) {
            unsigned e = dstP2[i1 + threadIdx.x];
            atomicAdd(&h[e >> BSH], slice[e & (BNODES - 1)]);
        }
    }
    __syncthreads();
    float4v* rowv = (float4v*)(pOut + (size_t)blockIdx.x * BNODES);
    float4v* hv = (float4v*)h;
    for (int t = threadIdx.x; t < BNODES / 4; t += DTB) rowv[t] = hv[t];
}

// ---------------- 1D fallback kernels (R11 path) ----------------

__global__ void deghist_kernel(const unsigned short* __restrict__ srcP, const unsigned* __restrict__ dstP,
                               const unsigned* __restrict__ curS, const unsigned* __restrict__ curD,
                               unsigned CAP, unsigned* __restrict__ pDeg, int Jlg) {
    __shared__ unsigned h[BNODES];
    {
        uint4v* hv = (uint4v*)h;
        for (int t = threadIdx.x; t < BNODES / 4; t += DTB) hv[t] = (uint4v)0u;
    }
    __syncthreads();
    int b = blockIdx.x >> Jlg;
    int j = blockIdx.x & ((1 << Jlg) - 1);
    unsigned s0 = (unsigned)b * CAP;
    {
        unsigned cD = curD[b * CSTR] - s0;
        unsigned lo = (unsigned)(((unsigned long long)cD * (unsigned)j) >> Jlg);
        unsigned hi = (unsigned)(((unsigned long long)cD * (unsigned)(j + 1)) >> Jlg);
        for (unsigned i = lo + threadIdx.x; i < hi; i += DTB)
            atomicAdd(&h[dstP[s0 + i] >> 19], 0x10000u);
    }
    {
        unsigned cS = curS[b * CSTR] - s0;
        unsigned lo = (unsigned)(((unsigned long long)cS * (unsigned)j) >> Jlg);
        unsigned hi = (unsigned)(((unsigned long long)cS * (unsigned)(j + 1)) >> Jlg);
        for (unsigned i = lo + threadIdx.x; i < hi; i += DTB)
            atomicAdd(&h[__builtin_nontemporal_load(&srcP[s0 + i])], 1u);
    }
    __syncthreads();
    uint4v* rowv = (uint4v*)(pDeg + (size_t)blockIdx.x * BNODES);
    uint4v* hv = (uint4v*)h;
    for (int t = threadIdx.x; t < BNODES / 4; t += DTB) rowv[t] = hv[t];
}

__global__ void prep_kernel(const unsigned* __restrict__ pDeg,
                            float* __restrict__ pio, float* __restrict__ h0s,
                            float* __restrict__ isiA, int Jlg, int Npad) {
    int i = blockIdx.x * TB + threadIdx.x;
    if (i >= Npad) return;
    int b = i >> BSH, l = i & (BNODES - 1);
    int J = 1 << Jlg;
    unsigned sum = 0;
    for (int j = 0; j < J; ++j)
        sum += __builtin_nontemporal_load(&pDeg[(size_t)((b << Jlg) + j) * BNODES + l]);
    float din = (float)(sum >> 16), dout = (float)(sum & 0xFFFFu);
    float a  = 1.0f / sqrtf(fmaxf(din, 1.0f));
    float bo = 1.0f / sqrtf(fmaxf(dout, 1.0f));
    pio[i]  = a * bo;
    h0s[i]  = din * bo;
    isiA[i] = a;
}

template <int LAST>
__global__ void wh_kernel(const unsigned* __restrict__ dstP, const unsigned* __restrict__ curD,
                          unsigned CAP, const float* __restrict__ table,
                          float* __restrict__ pOut, int Jlg) {
    __shared__ float h[BNODES];
    {
        float4v* hv = (float4v*)h;
        for (int t = threadIdx.x; t < BNODES / 4; t += DTB) hv[t] = (float4v)0.0f;
    }
    __syncthreads();
    int b = blockIdx.x >> Jlg;
    int j = blockIdx.x & ((1 << Jlg) - 1);
    unsigned s0 = (unsigned)b * CAP;
    unsigned cD = curD[b * CSTR] - s0;
    unsigned lo = (unsigned)(((unsigned long long)cD * (unsigned)j) >> Jlg);
    unsigned hi = (unsigned)(((unsigned long long)cD * (unsigned)(j + 1)) >> Jlg);
    unsigned i0 = (lo + 3u) & ~3u;
    unsigned i1 = hi & ~3u;
    if (i0 >= i1) {
        for (unsigned i = lo + threadIdx.x; i < hi; i += DTB) {
            unsigned e = dstP[s0 + i];
            atomicAdd(&h[e >> 19], table[e & 0x7FFFFu]);
        }
    } else {
        if (threadIdx.x < i0 - lo) {
            unsigned e = dstP[s0 + lo + threadIdx.x];
            atomicAdd(&h[e >> 19], table[e & 0x7FFFFu]);
        }
        const uint4v* qp = (const uint4v*)(dstP + s0);
        for (unsigned q = i0 / 4u + threadIdx.x; q < i1 / 4u; q += DTB) {
            uint4v e4 = LAST ? __builtin_nontemporal_load(qp + q) : qp[q];
            float t0 = table[e4.x & 0x7FFFFu];
            float t1 = table[e4.y & 0x7FFFFu];
            float t2 = table[e4.z & 0x7FFFFu];
            float t3 = table[e4.w & 0x7FFFFu];
            atomicAdd(&h[e4.x >> 19], t0);
            atomicAdd(&h[e4.y >> 19], t1);
            atomicAdd(&h[e4.z >> 19], t2);
            atomicAdd(&h[e4.w >> 19], t3);
        }
        if (threadIdx.x < hi - i1) {
            unsigned e = dstP[s0 + i1 + threadIdx.x];
            atomicAdd(&h[e >> 19], table[e & 0x7FFFFu]);
        }
    }
    __syncthreads();
    float4v* rowv = (float4v*)(pOut + (size_t)blockIdx.x * BNODES);
    float4v* hv = (float4v*)h;
    for (int t = threadIdx.x; t < BNODES / 4; t += DTB) rowv[t] = hv[t];
}

// ---------------- shared tail kernels ----------------

__global__ void mid_kernel(const float* __restrict__ pC, const float* __restrict__ pio,
                           float* __restrict__ sarr, int Jlg, int Npad) {
    int i = blockIdx.x * TB + threadIdx.x;
    if (i >= Npad) return;
    int b = i >> BSH, l = i & (BNODES - 1);
    int J = 1 << Jlg;
    float t1 = 0.0f;
    for (int j = 0; j < J; ++j)
        t1 += __builtin_nontemporal_load(&pC[(size_t)((b << Jlg) + j) * BNODES + l]);
    sarr[i] = t1 * pio[i];
}

__global__ void poolfinal_kernel(const float* __restrict__ pT, const float* __restrict__ isiA,
                                 const int* __restrict__ graph_ids,
                                 float* __restrict__ Xsum, int Jlg, int N) {
    int i = blockIdx.x * TB + threadIdx.x;
    bool valid = i < N;
    int ii = valid ? i : (N - 1);
    int b = ii >> BSH, l = ii & (BNODES - 1);
    int J = 1 << Jlg;
    float t2 = 0.0f;
    for (int j = 0; j < J; ++j)
        t2 += __builtin_nontemporal_load(&pT[(size_t)((b << Jlg) + j) * BNODES + l]);
    float x = valid ? t2 * isiA[ii] : 0.0f;
    int g = graph_ids[ii];
    int g0 = __shfl(g, 0, 64);
    bool uniform = __all((!valid) || (g == g0));
    if (uniform) {
#pragma unroll
        for (int off = 32; off >= 1; off >>= 1) x += __shfl_down(x, off, 64);
        if ((threadIdx.x & 63) == 0) atomicAdd(&Xsum[g0], x);
    } else if (valid) {
        atomicAdd(&Xsum[g], x);
    }
}

__global__ void final_kernel(const float* __restrict__ Xsum, const int* __restrict__ graph_ids,
                             const float* __restrict__ W1, const float* __restrict__ W2,
                             const float* __restrict__ Wlast,
                             float* __restrict__ out, int N, int GC) {
    int i = blockIdx.x * TB + threadIdx.x;
    if (i < GC) {
        int g = i >> 3, j = i & 7;
        int lo = 0, hi = N;
        while (lo < hi) { int m = (lo + hi) >> 1; if (graph_ids[m] < g) lo = m + 1; else hi = m; }
        int lo2 = lo, hi2 = N;
        while (lo2 < hi2) { int m = (lo2 + hi2) >> 1; if (graph_ids[m] < g + 1) lo2 = m + 1; else hi2 = m; }
        float c = (float)(lo2 - lo);
        float r = 0.0f;
#pragma unroll
        for (int cc = 0; cc < 8; ++cc) {
            float m = 0.0f;
#pragma unroll
            for (int k = 0; k < 8; ++k) m += fmaxf(W1[k], 0.0f) * W2[k * 8 + cc];
            r += fmaxf(m, 0.0f) * Wlast[cc * 8 + j];
        }
        out[i] = Xsum[g] / fmaxf(c, 1.0f) * r;
    }
}

// ---------------- fallback (atomic) path ----------------

__global__ void fb_deg_kernel(const int* __restrict__ src, const int* __restrict__ dst,
                              float* __restrict__ deg_out, float* __restrict__ deg_in, int E) {
    int i = blockIdx.x * TB + threadIdx.x;
    if (i < E) {
        atomicAdd(&deg_out[src[i]], 1.0f);
        atomicAdd(&deg_in[dst[i]], 1.0f);
    }
}

__global__ void fb_prep_kernel(const float* __restrict__ deg_in, const float* __restrict__ deg_out,
                               float* __restrict__ isi, float* __restrict__ iso,
                               float* __restrict__ h0s, int N) {
    int i = blockIdx.x * TB + threadIdx.x;
    if (i < N) {
        float di = deg_in[i], dn = deg_out[i];
        float a = 1.0f / sqrtf(fmaxf(di, 1.0f));
        float b = 1.0f / sqrtf(fmaxf(dn, 1.0f));
        isi[i] = a; iso[i] = b; h0s[i] = di * b;
    }
}

__global__ void fb_conv_kernel(const int* __restrict__ src, const int* __restrict__ dst,
                               const float* __restrict__ vals, float* __restrict__ t, int E) {
    int i = blockIdx.x * TB + threadIdx.x;
    if (i < E) atomicAdd(&t[dst[i]], vals[src[i]]);
}

__global__ void fb_mid_kernel(const float* __restrict__ agg1, const float* __restrict__ isi,
                              const float* __restrict__ iso, float* __restrict__ s, int N) {
    int i = blockIdx.x * TB + threadIdx.x;
    if (i < N) s[i] = agg1[i] * isi[i] * iso[i];
}

__global__ void fb_pool_kernel(const float* __restrict__ t2, const float* __restrict__ isi,
                               const int* __restrict__ graph_ids,
                               float* __restrict__ Xsum, float* __restrict__ counts, int N) {
    int i = blockIdx.x * TB + threadIdx.x;
    bool valid = i < N;
    int ii = valid ? i : (N - 1);
    float x = valid ? t2[ii] * isi[ii] : 0.0f;
    float cnt = valid ? 1.0f : 0.0f;
    int g = graph_ids[ii];
    int g0 = __shfl(g, 0, 64);
    bool uniform = __all((!valid) || (g == g0));
    if (uniform) {
#pragma unroll
        for (int off = 32; off >= 1; off >>= 1) {
            x += __shfl_down(x, off, 64);
            cnt += __shfl_down(cnt, off, 64);
        }
        if ((threadIdx.x & 63) == 0) { atomicAdd(&Xsum[g0], x); atomicAdd(&counts[g0], cnt); }
    } else if (valid) {
        atomicAdd(&Xsum[g], x); atomicAdd(&counts[g], 1.0f);
    }
}

__global__ void fb_final_kernel(const float* __restrict__ Xsum, const float* __restrict__ counts,
                                const float* __restrict__ W1, const float* __restrict__ W2,
                                const float* __restrict__ Wlast, float* __restrict__ out, int GC) {
    int i = blockIdx.x * TB + threadIdx.x;
    if (i < GC) {
        int g = i >> 3, j = i & 7;
        float r = 0.0f;
#pragma unroll
        for (int c = 0; c < 8; ++c) {
            float m = 0.0f;
#pragma unroll
            for (int k = 0; k < 8; ++k) m += fmaxf(W1[k], 0.0f) * W2[k * 8 + c];
            r += fmaxf(m, 0.0f) * Wlast[c * 8 + j];
        }
        out[i] = Xsum[g] / fmaxf(counts[g], 1.0f) * r;
    }
}

// ---------------- launch ----------------

extern "C" void kernel_launch(void* const* d_in, const int* in_sizes, int n_in,
                              void* d_out, int out_size, void* d_ws, size_t ws_size,
                              hipStream_t stream) {
    const float* W1        = (const float*)d_in[0];
    const float* W2        = (const float*)d_in[1];
    const float* Wlast     = (const float*)d_in[2];
    const int*   src       = (const int*)d_in[3];
    const int*   dst       = (const int*)d_in[4];
    const int*   graph_ids = (const int*)d_in[5];
    float* out = (float*)d_out;

    const int E = in_sizes[3];
    const int N = in_sizes[5];
    const int G = out_size / 8;

    int NB   = (N + BNODES - 1) >> BSH;
    int Npad = NB << BSH;
    int NCH  = (E + SCH - 1) / SCH;
    unsigned CAP = (unsigned)(((E / (NB > 0 ? NB : 1)) + 8192 + 511) & ~511);
    char* bp = (char*)d_ws;

    // ---- 2D layout (preferred) ----
    bool fast2D = false;
    size_t q_dstP = 0, q_dstP2 = 0, q_curD = 0, q_curC = 0, q_pio = 0, q_h0sar = 0,
           q_isi = 0, q_Xsum = 0;
    int cells = NB * NB;
    unsigned CAP2 = 0;
    int GS = (NB + GNUM - 1) / GNUM;
    if (N <= (1 << 19) && NB <= MAXNB && E >= 1) {
        CAP2 = (unsigned)(((E / (cells > 0 ? cells : 1)) + 768 + 127) & ~127);
        size_t off = 0;
        auto A = [&](size_t bytes) { size_t o = off; off = (off + bytes + 127) & ~(size_t)127; return o; };
        size_t partBytes = (size_t)NB * GNUM * BNODES * 4;      // pC/pT f32; also 2x u16 deg
        size_t dstPBytes = (size_t)NB * CAP * 4;
        q_dstP  = A(dstPBytes > partBytes ? dstPBytes : partBytes); // level-1 dstP, reused as partials
        q_dstP2 = A((size_t)cells * CAP2 * 4 + (size_t)CAP2 * 4);   // + slack row
        q_curD  = A((size_t)NB * CSTR * 4);
        q_curC  = A((size_t)cells * CSTR * 4);
        q_pio   = A((size_t)Npad * 4);
        q_h0sar = A((size_t)Npad * 4);
        q_isi   = A((size_t)Npad * 4);
        q_Xsum  = A((size_t)G * 4);
        fast2D = (off <= ws_size);
    }

    if (fast2D) {
        unsigned* dstP  = (unsigned*)(bp + q_dstP);
        unsigned* dstP2 = (unsigned*)(bp + q_dstP2);
        unsigned* curD  = (unsigned*)(bp + q_curD);
        unsigned* curC  = (unsigned*)(bp + q_curC);
        unsigned short* pDegIn  = (unsigned short*)(bp + q_dstP);
        unsigned short* pDegOut = pDegIn + (size_t)NB * GNUM * BNODES;
        float* pC   = (float*)(bp + q_dstP);
        float* pT   = (float*)(bp + q_dstP);
        float* pio  = (float*)(bp + q_pio);
        float* h0s  = (float*)(bp + q_h0sar);
        float* sarr = (float*)(bp + q_h0sar);
        float* isiA = (float*)(bp + q_isi);
        float* Xsum = (float*)(bp + q_Xsum);

        int gridNp = (Npad + TB - 1) / TB;
        int gridN  = (N + TB - 1) / TB;
        int mx = cells > G ? cells : G; if (NB > mx) mx = NB;
        int gridI  = (mx + TB - 1) / TB;
        int MAXCH  = (int)((CAP + SCH2 - 1) / SCH2);
        int NCH1 = (NCH + 1) / 2;
        int NCH2 = NCH - NCH1;

        init_kernel<<<gridI, TB, 0, stream>>>(curD, nullptr, curC, Xsum, NB, CAP, cells, CAP2, G);
        scatter_sort_kernel<<<NCH1, STB, 0, stream>>>(src, dst, curD, nullptr, dstP, nullptr, NB, E, 0);
        if (NCH2 > 0)
            scatter_sort_kernel<<<NCH2, STB, 0, stream>>>(src, dst, curD, nullptr, dstP, nullptr, NB, E, NCH1);
        subsort_kernel<<<NB * MAXCH, STB, 0, stream>>>(dstP, curD, curC, dstP2, CAP, CAP2, NB, MAXCH);
        degin2_kernel<<<NB * GNUM, DTB, 0, stream>>>(dstP2, curC, CAP2, pDegIn, NB, GS);
        degout2_kernel<<<NB * GNUM, DTB, 0, stream>>>(dstP2, curC, CAP2, pDegOut, NB, GS);
        prep2_kernel<<<gridNp, TB, 0, stream>>>(pDegIn, pDegOut, pio, h0s, isiA, Npad);
        wh2d_kernel<0><<<NB * GNUM, DTB, 0, stream>>>(dstP2, curC, CAP2, h0s, pC, NB, GS);
        mid_kernel<<<gridNp, TB, 0, stream>>>(pC, pio, sarr, GLG, Npad);
        wh2d_kernel<1><<<NB * GNUM, DTB, 0, stream>>>(dstP2, curC, CAP2, sarr, pT, NB, GS);
        poolfinal_kernel<<<gridN, TB, 0, stream>>>(pT, isiA, graph_ids, Xsum, GLG, N);
        final_kernel<<<(out_size + TB - 1) / TB, TB, 0, stream>>>(Xsum, graph_ids,
                                                                  W1, W2, Wlast, out, N, out_size);
        return;
    }

    // ---- 1D layout (R11 fallback) ----
    int Jlg = 4;
    size_t req = 0;
    size_t o_dstP, o_srcP, o_curD, o_curS, o_part, o_pio, o_h0sar, o_isi, o_Xsum;
    for (;; --Jlg) {
        int J = 1 << Jlg;
        size_t off = 0;
        auto A = [&](size_t bytes) { size_t o = off; off = (off + bytes + 127) & ~(size_t)127; return o; };
        o_dstP  = A((size_t)NB * CAP * 4);
        o_srcP  = A((size_t)NB * CAP * 2);
        o_curD  = A((size_t)NB * CSTR * 4);
        o_curS  = A((size_t)NB * CSTR * 4);
        o_part  = A((size_t)NB * J * BNODES * 4);
        o_pio   = A((size_t)Npad * 4);
        o_h0sar = A((size_t)Npad * 4);
        o_isi   = A((size_t)Npad * 4);
        o_Xsum  = A((size_t)G * 4);
        req = off;
        if (req <= ws_size || Jlg == 0) break;
    }

    bool fast = (N <= (1 << 19)) && (NB <= MAXNB) && (ws_size >= req) && (E >= 1);

    if (fast) {
        unsigned*       dstP = (unsigned*)(bp + o_dstP);
        unsigned short* srcP = (unsigned short*)(bp + o_srcP);
        unsigned* curD = (unsigned*)(bp + o_curD);
        unsigned* curS = (unsigned*)(bp + o_curS);
        unsigned* pDeg = (unsigned*)(bp + o_part);
        float*    pC   = (float*)(bp + o_part);
        float*    pT   = (float*)(bp + o_part);
        float* pio  = (float*)(bp + o_pio);
        float* h0s  = (float*)(bp + o_h0sar);
        float* sarr = (float*)(bp + o_h0sar);
        float* isiA = (float*)(bp + o_isi);
        float* Xsum = (float*)(bp + o_Xsum);

        int gridNp = (Npad + TB - 1) / TB;
        int gridN  = (N + TB - 1) / TB;
        int J = 1 << Jlg;
        int gridI = ((NB > G ? NB : G) + TB - 1) / TB;
        int NCH1 = (NCH + 1) / 2;
        int NCH2 = NCH - NCH1;

        init_kernel<<<gridI, TB, 0, stream>>>(curD, curS, nullptr, Xsum, NB, CAP, 0, 0, G);
        scatter_sort_kernel<<<NCH1, STB, 0, stream>>>(src, dst, curD, curS, dstP, srcP, NB, E, 0);
        if (NCH2 > 0)
            scatter_sort_kernel<<<NCH2, STB, 0, stream>>>(src, dst, curD, curS, dstP, srcP, NB, E, NCH1);
        deghist_kernel<<<NB * J, DTB, 0, stream>>>(srcP, dstP, curS, curD, CAP, pDeg, Jlg);
        prep_kernel<<<gridNp, TB, 0, stream>>>(pDeg, pio, h0s, isiA, Jlg, Npad);
        wh_kernel<0><<<NB * J, DTB, 0, stream>>>(dstP, curD, CAP, h0s, pC, Jlg);
        mid_kernel<<<gridNp, TB, 0, stream>>>(pC, pio, sarr, Jlg, Npad);
        wh_kernel<1><<<NB * J, DTB, 0, stream>>>(dstP, curD, CAP, sarr, pT, Jlg);
        poolfinal_kernel<<<gridN, TB, 0, stream>>>(pT, isiA, graph_ids, Xsum, Jlg, N);
        final_kernel<<<(out_size + TB - 1) / TB, TB, 0, stream>>>(Xsum, graph_ids,
                                                                  W1, W2, Wlast, out, N, out_size);
    } else {
        float* ws = (float*)d_ws;
        size_t f = 0;
        auto FA = [&](size_t n) { size_t o = f; f += (n + 3) & ~(size_t)3; return o; };
        size_t f_degin  = FA(N);
        size_t f_degout = FA(N);
        size_t f_agg1   = FA(N);
        size_t f_t2     = FA(N);
        size_t f_Xsum   = FA(G);
        size_t f_cnt    = FA(G);
        size_t zf = f;
        size_t f_isi = FA(N);
        size_t f_iso = FA(N);
        size_t f_h0s = FA(N);
        size_t f_s   = FA(N);
        hipMemsetAsync(ws, 0, zf * sizeof(float), stream);
        int gridE = (E + TB - 1) / TB;
        int gridN = (N + TB - 1) / TB;
        int gridO = (out_size + TB - 1) / TB;
        fb_deg_kernel<<<gridE, TB, 0, stream>>>(src, dst, ws + f_degout, ws + f_degin, E);
        fb_prep_kernel<<<gridN, TB, 0, stream>>>(ws + f_degin, ws + f_degout,
                                                 ws + f_isi, ws + f_iso, ws + f_h0s, N);
        fb_conv_kernel<<<gridE, TB, 0, stream>>>(src, dst, ws + f_h0s, ws + f_agg1, E);
        fb_mid_kernel<<<gridN, TB, 0, stream>>>(ws + f_agg1, ws + f_isi, ws + f_iso, ws + f_s, N);
        fb_conv_kernel<<<gridE, TB, 0, stream>>>(src, dst, ws + f_s, ws + f_t2, E);
        fb_pool_kernel<<<gridN, TB, 0, stream>>>(ws + f_t2, ws + f_isi, graph_ids,
                                                 ws + f_Xsum, ws + f_cnt, N);
        fb_final_kernel<<<gridO, TB, 0, stream>>>(ws + f_Xsum, ws + f_cnt, W1, W2, Wlast,
                                                  out, out_size);
    }
}

// Round 7
// 391.688 us; speedup vs baseline: 1.0733x; 1.0733x over previous
//
#include <hip/hip_runtime.h>

// GCN rank-1 collapse + 2-level counting-sort partition (R13).
// R12 post-mortem: slice-staging wh2d cut FETCH 28->21MB but ran 73us
// (occupancy 63->34% from 64KB LDS; per-sb barrier pairs serialized).
// Lesson: after 2-level sort each cell's gathers span ONE 32KB table
// slice = exactly L1 size -> gather from GLOBAL, let L1 hold the slice.
// R13: (1) wh2g = global gather, h-only 32KB LDS, no inner barriers,
// 4-wide ILP; (2) deg2 = fused packed degree pass (row cells -> din<<16,
// column cells -> dout) one kernel instead of two; (3) prep unpacks
// before summing (no cross-partial carry). Partition kernels unchanged.

#define TB 256
#define DTB 512
#define STB 512
#define BSH 13
#define BNODES 8192
#define MAXNB 64
#define SCH 4096
#define SCH4 (SCH / 4)
#define SCH2 4096
#define EPT 8
#define CSTR 16
#define GLG 4
#define GNUM 16
#define INVB 0xFFFFFFFFu

typedef __attribute__((ext_vector_type(4))) int int4v;
typedef __attribute__((ext_vector_type(4))) unsigned uint4v;
typedef __attribute__((ext_vector_type(2))) unsigned uint2v;
typedef __attribute__((ext_vector_type(4))) float float4v;

__global__ void init_kernel(unsigned* __restrict__ curD, unsigned* __restrict__ curS,
                            unsigned* __restrict__ curC, float* __restrict__ Xsum,
                            int NB, unsigned CAP, int cells, unsigned CAP2, int G) {
    int i = blockIdx.x * TB + threadIdx.x;
    if (i < NB) curD[i * CSTR] = (unsigned)i * CAP;
    if (curS && i < NB) curS[i * CSTR] = (unsigned)i * CAP;
    if (curC && i < cells) curC[i * CSTR] = (unsigned)i * CAP2;
    if (i < G) Xsum[i] = 0.0f;
}

// Level-1: partition edges by dst-block. srcP==nullptr -> 2D mode (no S side).
__global__ void scatter_sort_kernel(const int* __restrict__ src, const int* __restrict__ dst,
                                    unsigned* __restrict__ curD, unsigned* __restrict__ curS,
                                    unsigned* __restrict__ dstP, unsigned short* __restrict__ srcP,
                                    int NB, int E, int blk0) {
    __shared__ unsigned cntD[MAXNB], cntS[MAXNB];
    __shared__ unsigned deltaD[MAXNB], deltaS[MAXNB];
    __shared__ unsigned totD_s, totS_s;
    __shared__ unsigned payD[SCH];
    __shared__ unsigned short valS[SCH];
    __shared__ unsigned char mapD[SCH], mapS[SCH];

    int tid = threadIdx.x;
    if (tid < MAXNB) { cntD[tid] = 0u; cntS[tid] = 0u; }
    __syncthreads();

    unsigned sA[EPT], dA[EPT], bD[EPT], bS[EPT];
    int blk = blockIdx.x + blk0;
#pragma unroll
    for (int v = 0; v < 2; ++v) {
        int q = blk * SCH4 + v * STB + tid;
        int be = q * 4;
        if (be + 3 < E) {
            int4v s4 = __builtin_nontemporal_load((const int4v*)src + q);
            int4v d4 = __builtin_nontemporal_load((const int4v*)dst + q);
#pragma unroll
            for (int k = 0; k < 4; ++k) {
                sA[v*4+k] = (unsigned)s4[k];
                dA[v*4+k] = (unsigned)d4[k];
                bD[v*4+k] = dA[v*4+k] >> BSH;
                bS[v*4+k] = sA[v*4+k] >> BSH;
            }
        } else {
#pragma unroll
            for (int k = 0; k < 4; ++k) {
                int j = be + k;
                if (j < E) {
                    sA[v*4+k] = (unsigned)src[j];
                    dA[v*4+k] = (unsigned)dst[j];
                    bD[v*4+k] = dA[v*4+k] >> BSH;
                    bS[v*4+k] = sA[v*4+k] >> BSH;
                } else {
                    bD[v*4+k] = INVB; bS[v*4+k] = INVB;
                    sA[v*4+k] = 0u; dA[v*4+k] = 0u;
                }
            }
        }
    }

#pragma unroll
    for (int k = 0; k < EPT; ++k) {
        if (bD[k] != INVB) {
            atomicAdd(&cntD[bD[k]], 1u);
            if (srcP) atomicAdd(&cntS[bS[k]], 1u);
        }
    }
    __syncthreads();

    int wv = tid >> 6, ln = tid & 63;
    if (wv == 0) {
        unsigned x = (ln < NB) ? cntD[ln] : 0u;
        unsigned inc = x;
#pragma unroll
        for (int o = 1; o < 64; o <<= 1) {
            unsigned y = __shfl_up(inc, o, 64);
            if (ln >= o) inc += y;
        }
        unsigned exc = inc - x;
        if (ln < NB) {
            unsigned gb = atomicAdd(&curD[ln * CSTR], x);
            deltaD[ln] = gb - exc;
            cntD[ln] = exc;
        }
        if (ln == 63) totD_s = inc;
    } else if (wv == 1 && srcP) {
        unsigned x = (ln < NB) ? cntS[ln] : 0u;
        unsigned inc = x;
#pragma unroll
        for (int o = 1; o < 64; o <<= 1) {
            unsigned y = __shfl_up(inc, o, 64);
            if (ln >= o) inc += y;
        }
        unsigned exc = inc - x;
        if (ln < NB) {
            unsigned gb = atomicAdd(&curS[ln * CSTR], x);
            deltaS[ln] = gb - exc;
            cntS[ln] = exc;
        }
        if (ln == 63) totS_s = inc;
    }
    __syncthreads();

#pragma unroll
    for (int k = 0; k < EPT; ++k) {
        if (bD[k] != INVB) {
            unsigned p = atomicAdd(&cntD[bD[k]], 1u);
            payD[p] = ((dA[k] & (BNODES - 1)) << 19) | sA[k];
            mapD[p] = (unsigned char)bD[k];
            if (srcP) {
                unsigned p2 = atomicAdd(&cntS[bS[k]], 1u);
                valS[p2] = (unsigned short)(sA[k] & (BNODES - 1));
                mapS[p2] = (unsigned char)bS[k];
            }
        }
    }
    __syncthreads();

    unsigned tD = totD_s;
    for (unsigned i = tid; i < tD; i += STB) {
        unsigned b = mapD[i];
        dstP[deltaD[b] + i] = payD[i];
    }
    if (srcP) {
        unsigned tS = totS_s;
        for (unsigned i = tid; i < tS; i += STB) {
            unsigned b = mapS[i];
            srcP[deltaS[b] + i] = valS[i];
        }
    }
}

// Level-2: split each dst-bucket by src-block into cells.
// Payload out: (dst_local:13 << 13) | src_local:13.
__global__ void subsort_kernel(const unsigned* __restrict__ dstP, const unsigned* __restrict__ curD,
                               unsigned* __restrict__ curC, unsigned* __restrict__ dstP2,
                               unsigned CAP, unsigned CAP2, int NB, int MAXCH) {
    __shared__ unsigned cnt2[MAXNB], delta2[MAXNB];
    __shared__ unsigned tot_s;
    __shared__ unsigned pay[SCH2];
    __shared__ unsigned char map2[SCH2];

    int db = blockIdx.x / MAXCH, c = blockIdx.x % MAXCH;
    unsigned s = (unsigned)db * CAP + (unsigned)c * SCH2;
    unsigned e = curD[db * CSTR];            // absolute end of db region
    if (s >= e) return;                      // uniform early-out
    unsigned n = e - s; if (n > SCH2) n = SCH2;

    int tid = threadIdx.x;
    if (tid < MAXNB) cnt2[tid] = 0u;
    __syncthreads();

    unsigned pl[EPT], bk[EPT];
#pragma unroll
    for (int v = 0; v < 2; ++v) {
        unsigned q = (unsigned)(v * STB + tid);
        unsigned base = q * 4u;
        if (base + 3u < n) {
            uint4v p4 = *((const uint4v*)(dstP + s) + q);
#pragma unroll
            for (int k = 0; k < 4; ++k) {
                pl[v*4+k] = p4[k];
                bk[v*4+k] = (p4[k] & 0x7FFFFu) >> BSH;
            }
        } else {
#pragma unroll
            for (int k = 0; k < 4; ++k) {
                unsigned j = base + (unsigned)k;
                if (j < n) {
                    pl[v*4+k] = dstP[s + j];
                    bk[v*4+k] = (pl[v*4+k] & 0x7FFFFu) >> BSH;
                } else { bk[v*4+k] = INVB; pl[v*4+k] = 0u; }
            }
        }
    }

#pragma unroll
    for (int k = 0; k < EPT; ++k)
        if (bk[k] != INVB) atomicAdd(&cnt2[bk[k]], 1u);
    __syncthreads();

    if (tid < 64) {
        int ln = tid;
        unsigned x = cnt2[ln];
        unsigned inc = x;
#pragma unroll
        for (int o = 1; o < 64; o <<= 1) {
            unsigned y = __shfl_up(inc, o, 64);
            if (ln >= o) inc += y;
        }
        unsigned exc = inc - x;
        if (ln < NB) {
            unsigned gb = atomicAdd(&curC[((unsigned)db * NB + ln) * CSTR], x);
            delta2[ln] = gb - exc;
            cnt2[ln] = exc;
        }
        if (ln == 63) tot_s = inc;
    }
    __syncthreads();

#pragma unroll
    for (int k = 0; k < EPT; ++k) {
        if (bk[k] != INVB) {
            unsigned p = atomicAdd(&cnt2[bk[k]], 1u);
            pay[p] = ((pl[k] >> 19) << BSH) | (pl[k] & (BNODES - 1));
            map2[p] = (unsigned char)bk[k];
        }
    }
    __syncthreads();

    unsigned tot = tot_s;
    for (unsigned i = tid; i < tot; i += STB) {
        unsigned b = map2[i];
        dstP2[delta2[b] + i] = pay[i];
    }
}

// Fused packed degrees: block (b,g) walks row cells (b,c) for deg_in
// (+0x10000 on dst_local) and column cells (c,b) for deg_out (+1 on
// src_local). Per-partial fields can't overflow (4 cells x CAP2 < 65536).
__global__ void deg2_kernel(const unsigned* __restrict__ dstP2, const unsigned* __restrict__ curC,
                            unsigned CAP2, unsigned* __restrict__ pDeg, int NB, int GS) {
    __shared__ unsigned h[BNODES];
    {
        uint4v* hv = (uint4v*)h;
        for (int t = threadIdx.x; t < BNODES / 4; t += DTB) hv[t] = (uint4v)0u;
    }
    __syncthreads();
    int b = blockIdx.x >> GLG, g = blockIdx.x & (GNUM - 1);
    int cEnd = (g + 1) * GS; if (cEnd > NB) cEnd = NB;
    for (int c = g * GS; c < cEnd; ++c) {          // row cells: deg_in
        unsigned cell = (unsigned)(b * NB + c);
        unsigned lo = cell * CAP2;
        unsigned hi = curC[cell * CSTR];
        unsigned i1 = hi & ~3u;
        const uint4v* qp = (const uint4v*)(dstP2 + lo);
        for (unsigned q = threadIdx.x; q < (i1 - lo) / 4u; q += DTB) {
            uint4v e4 = qp[q];
            atomicAdd(&h[e4.x >> BSH], 0x10000u);
            atomicAdd(&h[e4.y >> BSH], 0x10000u);
            atomicAdd(&h[e4.z >> BSH], 0x10000u);
            atomicAdd(&h[e4.w >> BSH], 0x10000u);
        }
        if (threadIdx.x < hi - i1)
            atomicAdd(&h[dstP2[i1 + threadIdx.x] >> BSH], 0x10000u);
    }
    for (int c = g * GS; c < cEnd; ++c) {          // column cells: deg_out
        unsigned cell = (unsigned)(c * NB + b);
        unsigned lo = cell * CAP2;
        unsigned hi = curC[cell * CSTR];
        unsigned i1 = hi & ~3u;
        const uint4v* qp = (const uint4v*)(dstP2 + lo);
        for (unsigned q = threadIdx.x; q < (i1 - lo) / 4u; q += DTB) {
            uint4v e4 = qp[q];
            atomicAdd(&h[e4.x & (BNODES - 1)], 1u);
            atomicAdd(&h[e4.y & (BNODES - 1)], 1u);
            atomicAdd(&h[e4.z & (BNODES - 1)], 1u);
            atomicAdd(&h[e4.w & (BNODES - 1)], 1u);
        }
        if (threadIdx.x < hi - i1)
            atomicAdd(&h[dstP2[i1 + threadIdx.x] & (BNODES - 1)], 1u);
    }
    __syncthreads();
    uint4v* rowv = (uint4v*)(pDeg + (size_t)blockIdx.x * BNODES);
    uint4v* hv = (uint4v*)h;
    for (int t = threadIdx.x; t < BNODES / 4; t += DTB) rowv[t] = hv[t];
}

__global__ void prep2_kernel(const unsigned* __restrict__ pDeg,
                             float* __restrict__ pio, float* __restrict__ h0s,
                             float* __restrict__ isiA, int Npad) {
    int i = blockIdx.x * TB + threadIdx.x;
    if (i >= Npad) return;
    int b = i >> BSH, l = i & (BNODES - 1);
    unsigned din_u = 0, dout_u = 0;
    for (int g = 0; g < GNUM; ++g) {
        unsigned v = __builtin_nontemporal_load(&pDeg[(size_t)(b * GNUM + g) * BNODES + l]);
        din_u  += v >> 16;          // unpack BEFORE summing: no cross-partial carry
        dout_u += v & 0xFFFFu;
    }
    float din = (float)din_u, dout = (float)dout_u;
    float a  = 1.0f / sqrtf(fmaxf(din, 1.0f));
    float bo = 1.0f / sqrtf(fmaxf(dout, 1.0f));
    pio[i]  = a * bo;
    h0s[i]  = din * bo;
    isiA[i] = a;
}

// 2D weighted histogram, global gather: per cell the table addresses span
// one 32KB slice -> L1-resident. h-only LDS (32KB), no inner barriers.
template <int LAST>
__global__ void wh2g_kernel(const unsigned* __restrict__ dstP2, const unsigned* __restrict__ curC,
                            unsigned CAP2, const float* __restrict__ table,
                            float* __restrict__ pOut, int NB, int GS) {
    __shared__ float h[BNODES];
    {
        float4v* hv = (float4v*)h;
        for (int t = threadIdx.x; t < BNODES / 4; t += DTB) hv[t] = (float4v)0.0f;
    }
    __syncthreads();
    int db = blockIdx.x >> GLG, g = blockIdx.x & (GNUM - 1);
    int sbEnd = (g + 1) * GS; if (sbEnd > NB) sbEnd = NB;
    for (int sb = g * GS; sb < sbEnd; ++sb) {
        const float* tb = table + ((size_t)sb << BSH);
        unsigned cell = (unsigned)(db * NB + sb);
        unsigned lo = cell * CAP2;       // CAP2 128-aligned -> 16B-aligned base
        unsigned hi = curC[cell * CSTR];
        unsigned i1 = hi & ~3u;
        const uint4v* qp = (const uint4v*)(dstP2 + lo);
        for (unsigned q = threadIdx.x; q < (i1 - lo) / 4u; q += DTB) {
            uint4v e4 = LAST ? __builtin_nontemporal_load(qp + q) : qp[q];
            float t0 = tb[e4.x & (BNODES - 1)];
            float t1 = tb[e4.y & (BNODES - 1)];
            float t2 = tb[e4.z & (BNODES - 1)];
            float t3 = tb[e4.w & (BNODES - 1)];
            atomicAdd(&h[e4.x >> BSH], t0);
            atomicAdd(&h[e4.y >> BSH], t1);
            atomicAdd(&h[e4.z >> BSH], t2);
            atomicAdd(&h[e4.w >> BSH], t3);
        }
        if (threadIdx.x < hi - i1) {
            unsigned e = dstP2[i1 + threadIdx.x];
            atomicAdd(&h[e >> BSH], tb[e & (BNODES - 1)]);
        }
    }
    __syncthreads();
    float4v* rowv = (float4v*)(pOut + (size_t)blockIdx.x * BNODES);
    float4v* hv = (float4v*)h;
    for (int t = threadIdx.x; t < BNODES / 4; t += DTB) rowv[t] = hv[t];
}

// ---------------- 1D fallback kernels (R11 path) ----------------

__global__ void deghist_kernel(const unsigned short* __restrict__ srcP, const unsigned* __restrict__ dstP,
                               const unsigned* __restrict__ curS, const unsigned* __restrict__ curD,
                               unsigned CAP, unsigned* __restrict__ pDeg, int Jlg) {
    __shared__ unsigned h[BNODES];
    {
        uint4v* hv = (uint4v*)h;
        for (int t = threadIdx.x; t < BNODES / 4; t += DTB) hv[t] = (uint4v)0u;
    }
    __syncthreads();
    int b = blockIdx.x >> Jlg;
    int j = blockIdx.x & ((1 << Jlg) - 1);
    unsigned s0 = (unsigned)b * CAP;
    {
        unsigned cD = curD[b * CSTR] - s0;
        unsigned lo = (unsigned)(((unsigned long long)cD * (unsigned)j) >> Jlg);
        unsigned hi = (unsigned)(((unsigned long long)cD * (unsigned)(j + 1)) >> Jlg);
        for (unsigned i = lo + threadIdx.x; i < hi; i += DTB)
            atomicAdd(&h[dstP[s0 + i] >> 19], 0x10000u);
    }
    {
        unsigned cS = curS[b * CSTR] - s0;
        unsigned lo = (unsigned)(((unsigned long long)cS * (unsigned)j) >> Jlg);
        unsigned hi = (unsigned)(((unsigned long long)cS * (unsigned)(j + 1)) >> Jlg);
        for (unsigned i = lo + threadIdx.x; i < hi; i += DTB)
            atomicAdd(&h[__builtin_nontemporal_load(&srcP[s0 + i])], 1u);
    }
    __syncthreads();
    uint4v* rowv = (uint4v*)(pDeg + (size_t)blockIdx.x * BNODES);
    uint4v* hv = (uint4v*)h;
    for (int t = threadIdx.x; t < BNODES / 4; t += DTB) rowv[t] = hv[t];
}

__global__ void prep_kernel(const unsigned* __restrict__ pDeg,
                            float* __restrict__ pio, float* __restrict__ h0s,
                            float* __restrict__ isiA, int Jlg, int Npad) {
    int i = blockIdx.x * TB + threadIdx.x;
    if (i >= Npad) return;
    int b = i >> BSH, l = i & (BNODES - 1);
    int J = 1 << Jlg;
    unsigned din_u = 0, dout_u = 0;
    for (int j = 0; j < J; ++j) {
        unsigned v = __builtin_nontemporal_load(&pDeg[(size_t)((b << Jlg) + j) * BNODES + l]);
        din_u += v >> 16; dout_u += v & 0xFFFFu;
    }
    float din = (float)din_u, dout = (float)dout_u;
    float a  = 1.0f / sqrtf(fmaxf(din, 1.0f));
    float bo = 1.0f / sqrtf(fmaxf(dout, 1.0f));
    pio[i]  = a * bo;
    h0s[i]  = din * bo;
    isiA[i] = a;
}

template <int LAST>
__global__ void wh_kernel(const unsigned* __restrict__ dstP, const unsigned* __restrict__ curD,
                          unsigned CAP, const float* __restrict__ table,
                          float* __restrict__ pOut, int Jlg) {
    __shared__ float h[BNODES];
    {
        float4v* hv = (float4v*)h;
        for (int t = threadIdx.x; t < BNODES / 4; t += DTB) hv[t] = (float4v)0.0f;
    }
    __syncthreads();
    int b = blockIdx.x >> Jlg;
    int j = blockIdx.x & ((1 << Jlg) - 1);
    unsigned s0 = (unsigned)b * CAP;
    unsigned cD = curD[b * CSTR] - s0;
    unsigned lo = (unsigned)(((unsigned long long)cD * (unsigned)j) >> Jlg);
    unsigned hi = (unsigned)(((unsigned long long)cD * (unsigned)(j + 1)) >> Jlg);
    unsigned i0 = (lo + 3u) & ~3u;
    unsigned i1 = hi & ~3u;
    if (i0 >= i1) {
        for (unsigned i = lo + threadIdx.x; i < hi; i += DTB) {
            unsigned e = dstP[s0 + i];
            atomicAdd(&h[e >> 19], table[e & 0x7FFFFu]);
        }
    } else {
        if (threadIdx.x < i0 - lo) {
            unsigned e = dstP[s0 + lo + threadIdx.x];
            atomicAdd(&h[e >> 19], table[e & 0x7FFFFu]);
        }
        const uint4v* qp = (const uint4v*)(dstP + s0);
        for (unsigned q = i0 / 4u + threadIdx.x; q < i1 / 4u; q += DTB) {
            uint4v e4 = LAST ? __builtin_nontemporal_load(qp + q) : qp[q];
            float t0 = table[e4.x & 0x7FFFFu];
            float t1 = table[e4.y & 0x7FFFFu];
            float t2 = table[e4.z & 0x7FFFFu];
            float t3 = table[e4.w & 0x7FFFFu];
            atomicAdd(&h[e4.x >> 19], t0);
            atomicAdd(&h[e4.y >> 19], t1);
            atomicAdd(&h[e4.z >> 19], t2);
            atomicAdd(&h[e4.w >> 19], t3);
        }
        if (threadIdx.x < hi - i1) {
            unsigned e = dstP[s0 + i1 + threadIdx.x];
            atomicAdd(&h[e >> 19], table[e & 0x7FFFFu]);
        }
    }
    __syncthreads();
    float4v* rowv = (float4v*)(pOut + (size_t)blockIdx.x * BNODES);
    float4v* hv = (float4v*)h;
    for (int t = threadIdx.x; t < BNODES / 4; t += DTB) rowv[t] = hv[t];
}

// ---------------- shared tail kernels ----------------

__global__ void mid_kernel(const float* __restrict__ pC, const float* __restrict__ pio,
                           float* __restrict__ sarr, int Jlg, int Npad) {
    int i = blockIdx.x * TB + threadIdx.x;
    if (i >= Npad) return;
    int b = i >> BSH, l = i & (BNODES - 1);
    int J = 1 << Jlg;
    float t1 = 0.0f;
    for (int j = 0; j < J; ++j)
        t1 += __builtin_nontemporal_load(&pC[(size_t)((b << Jlg) + j) * BNODES + l]);
    sarr[i] = t1 * pio[i];
}

__global__ void poolfinal_kernel(const float* __restrict__ pT, const float* __restrict__ isiA,
                                 const int* __restrict__ graph_ids,
                                 float* __restrict__ Xsum, int Jlg, int N) {
    int i = blockIdx.x * TB + threadIdx.x;
    bool valid = i < N;
    int ii = valid ? i : (N - 1);
    int b = ii >> BSH, l = ii & (BNODES - 1);
    int J = 1 << Jlg;
    float t2 = 0.0f;
    for (int j = 0; j < J; ++j)
        t2 += __builtin_nontemporal_load(&pT[(size_t)((b << Jlg) + j) * BNODES + l]);
    float x = valid ? t2 * isiA[ii] : 0.0f;
    int g = graph_ids[ii];
    int g0 = __shfl(g, 0, 64);
    bool uniform = __all((!valid) || (g == g0));
    if (uniform) {
#pragma unroll
        for (int off = 32; off >= 1; off >>= 1) x += __shfl_down(x, off, 64);
        if ((threadIdx.x & 63) == 0) atomicAdd(&Xsum[g0], x);
    } else if (valid) {
        atomicAdd(&Xsum[g], x);
    }
}

__global__ void final_kernel(const float* __restrict__ Xsum, const int* __restrict__ graph_ids,
                             const float* __restrict__ W1, const float* __restrict__ W2,
                             const float* __restrict__ Wlast,
                             float* __restrict__ out, int N, int GC) {
    int i = blockIdx.x * TB + threadIdx.x;
    if (i < GC) {
        int g = i >> 3, j = i & 7;
        int lo = 0, hi = N;
        while (lo < hi) { int m = (lo + hi) >> 1; if (graph_ids[m] < g) lo = m + 1; else hi = m; }
        int lo2 = lo, hi2 = N;
        while (lo2 < hi2) { int m = (lo2 + hi2) >> 1; if (graph_ids[m] < g + 1) lo2 = m + 1; else hi2 = m; }
        float c = (float)(lo2 - lo);
        float r = 0.0f;
#pragma unroll
        for (int cc = 0; cc < 8; ++cc) {
            float m = 0.0f;
#pragma unroll
            for (int k = 0; k < 8; ++k) m += fmaxf(W1[k], 0.0f) * W2[k * 8 + cc];
            r += fmaxf(m, 0.0f) * Wlast[cc * 8 + j];
        }
        out[i] = Xsum[g] / fmaxf(c, 1.0f) * r;
    }
}

// ---------------- fallback (atomic) path ----------------

__global__ void fb_deg_kernel(const int* __restrict__ src, const int* __restrict__ dst,
                              float* __restrict__ deg_out, float* __restrict__ deg_in, int E) {
    int i = blockIdx.x * TB + threadIdx.x;
    if (i < E) {
        atomicAdd(&deg_out[src[i]], 1.0f);
        atomicAdd(&deg_in[dst[i]], 1.0f);
    }
}

__global__ void fb_prep_kernel(const float* __restrict__ deg_in, const float* __restrict__ deg_out,
                               float* __restrict__ isi, float* __restrict__ iso,
                               float* __restrict__ h0s, int N) {
    int i = blockIdx.x * TB + threadIdx.x;
    if (i < N) {
        float di = deg_in[i], dn = deg_out[i];
        float a = 1.0f / sqrtf(fmaxf(di, 1.0f));
        float b = 1.0f / sqrtf(fmaxf(dn, 1.0f));
        isi[i] = a; iso[i] = b; h0s[i] = di * b;
    }
}

__global__ void fb_conv_kernel(const int* __restrict__ src, const int* __restrict__ dst,
                               const float* __restrict__ vals, float* __restrict__ t, int E) {
    int i = blockIdx.x * TB + threadIdx.x;
    if (i < E) atomicAdd(&t[dst[i]], vals[src[i]]);
}

__global__ void fb_mid_kernel(const float* __restrict__ agg1, const float* __restrict__ isi,
                              const float* __restrict__ iso, float* __restrict__ s, int N) {
    int i = blockIdx.x * TB + threadIdx.x;
    if (i < N) s[i] = agg1[i] * isi[i] * iso[i];
}

__global__ void fb_pool_kernel(const float* __restrict__ t2, const float* __restrict__ isi,
                               const int* __restrict__ graph_ids,
                               float* __restrict__ Xsum, float* __restrict__ counts, int N) {
    int i = blockIdx.x * TB + threadIdx.x;
    bool valid = i < N;
    int ii = valid ? i : (N - 1);
    float x = valid ? t2[ii] * isi[ii] : 0.0f;
    float cnt = valid ? 1.0f : 0.0f;
    int g = graph_ids[ii];
    int g0 = __shfl(g, 0, 64);
    bool uniform = __all((!valid) || (g == g0));
    if (uniform) {
#pragma unroll
        for (int off = 32; off >= 1; off >>= 1) {
            x += __shfl_down(x, off, 64);
            cnt += __shfl_down(cnt, off, 64);
        }
        if ((threadIdx.x & 63) == 0) { atomicAdd(&Xsum[g0], x); atomicAdd(&counts[g0], cnt); }
    } else if (valid) {
        atomicAdd(&Xsum[g], x); atomicAdd(&counts[g], 1.0f);
    }
}

__global__ void fb_final_kernel(const float* __restrict__ Xsum, const float* __restrict__ counts,
                                const float* __restrict__ W1, const float* __restrict__ W2,
                                const float* __restrict__ Wlast, float* __restrict__ out, int GC) {
    int i = blockIdx.x * TB + threadIdx.x;
    if (i < GC) {
        int g = i >> 3, j = i & 7;
        float r = 0.0f;
#pragma unroll
        for (int c = 0; c < 8; ++c) {
            float m = 0.0f;
#pragma unroll
            for (int k = 0; k < 8; ++k) m += fmaxf(W1[k], 0.0f) * W2[k * 8 + c];
            r += fmaxf(m, 0.0f) * Wlast[c * 8 + j];
        }
        out[i] = Xsum[g] / fmaxf(counts[g], 1.0f) * r;
    }
}

// ---------------- launch ----------------

extern "C" void kernel_launch(void* const* d_in, const int* in_sizes, int n_in,
                              void* d_out, int out_size, void* d_ws, size_t ws_size,
                              hipStream_t stream) {
    const float* W1        = (const float*)d_in[0];
    const float* W2        = (const float*)d_in[1];
    const float* Wlast     = (const float*)d_in[2];
    const int*   src       = (const int*)d_in[3];
    const int*   dst       = (const int*)d_in[4];
    const int*   graph_ids = (const int*)d_in[5];
    float* out = (float*)d_out;

    const int E = in_sizes[3];
    const int N = in_sizes[5];
    const int G = out_size / 8;

    int NB   = (N + BNODES - 1) >> BSH;
    int Npad = NB << BSH;
    int NCH  = (E + SCH - 1) / SCH;
    unsigned CAP = (unsigned)(((E / (NB > 0 ? NB : 1)) + 8192 + 511) & ~511);
    char* bp = (char*)d_ws;

    // ---- 2D layout (preferred) ----
    bool fast2D = false;
    size_t q_dstP = 0, q_dstP2 = 0, q_curD = 0, q_curC = 0, q_pio = 0, q_h0sar = 0,
           q_isi = 0, q_Xsum = 0;
    int cells = NB * NB;
    unsigned CAP2 = 0;
    int GS = (NB + GNUM - 1) / GNUM;
    if (N <= (1 << 19) && NB <= MAXNB && E >= 1) {
        CAP2 = (unsigned)(((E / (cells > 0 ? cells : 1)) + 768 + 127) & ~127);
        size_t off = 0;
        auto A = [&](size_t bytes) { size_t o = off; off = (off + bytes + 127) & ~(size_t)127; return o; };
        size_t partBytes = (size_t)NB * GNUM * BNODES * 4;      // pDeg/pC/pT (aliased)
        size_t dstPBytes = (size_t)NB * CAP * 4;
        q_dstP  = A(dstPBytes > partBytes ? dstPBytes : partBytes);
        q_dstP2 = A((size_t)cells * CAP2 * 4 + (size_t)CAP2 * 4);   // + slack row
        q_curD  = A((size_t)NB * CSTR * 4);
        q_curC  = A((size_t)cells * CSTR * 4);
        q_pio   = A((size_t)Npad * 4);
        q_h0sar = A((size_t)Npad * 4);
        q_isi   = A((size_t)Npad * 4);
        q_Xsum  = A((size_t)G * 4);
        fast2D = (off <= ws_size);
    }

    if (fast2D) {
        unsigned* dstP  = (unsigned*)(bp + q_dstP);
        unsigned* dstP2 = (unsigned*)(bp + q_dstP2);
        unsigned* curD  = (unsigned*)(bp + q_curD);
        unsigned* curC  = (unsigned*)(bp + q_curC);
        unsigned* pDeg  = (unsigned*)(bp + q_dstP);   // alias over dead dstP
        float* pC   = (float*)(bp + q_dstP);
        float* pT   = (float*)(bp + q_dstP);
        float* pio  = (float*)(bp + q_pio);
        float* h0s  = (float*)(bp + q_h0sar);
        float* sarr = (float*)(bp + q_h0sar);
        float* isiA = (float*)(bp + q_isi);
        float* Xsum = (float*)(bp + q_Xsum);

        int gridNp = (Npad + TB - 1) / TB;
        int gridN  = (N + TB - 1) / TB;
        int mx = cells > G ? cells : G; if (NB > mx) mx = NB;
        int gridI  = (mx + TB - 1) / TB;
        int MAXCH  = (int)((CAP + SCH2 - 1) / SCH2);
        int NCH1 = (NCH + 1) / 2;
        int NCH2 = NCH - NCH1;

        init_kernel<<<gridI, TB, 0, stream>>>(curD, nullptr, curC, Xsum, NB, CAP, cells, CAP2, G);
        scatter_sort_kernel<<<NCH1, STB, 0, stream>>>(src, dst, curD, nullptr, dstP, nullptr, NB, E, 0);
        if (NCH2 > 0)
            scatter_sort_kernel<<<NCH2, STB, 0, stream>>>(src, dst, curD, nullptr, dstP, nullptr, NB, E, NCH1);
        subsort_kernel<<<NB * MAXCH, STB, 0, stream>>>(dstP, curD, curC, dstP2, CAP, CAP2, NB, MAXCH);
        deg2_kernel<<<NB * GNUM, DTB, 0, stream>>>(dstP2, curC, CAP2, pDeg, NB, GS);
        prep2_kernel<<<gridNp, TB, 0, stream>>>(pDeg, pio, h0s, isiA, Npad);
        wh2g_kernel<0><<<NB * GNUM, DTB, 0, stream>>>(dstP2, curC, CAP2, h0s, pC, NB, GS);
        mid_kernel<<<gridNp, TB, 0, stream>>>(pC, pio, sarr, GLG, Npad);
        wh2g_kernel<1><<<NB * GNUM, DTB, 0, stream>>>(dstP2, curC, CAP2, sarr, pT, NB, GS);
        poolfinal_kernel<<<gridN, TB, 0, stream>>>(pT, isiA, graph_ids, Xsum, GLG, N);
        final_kernel<<<(out_size + TB - 1) / TB, TB, 0, stream>>>(Xsum, graph_ids,
                                                                  W1, W2, Wlast, out, N, out_size);
        return;
    }

    // ---- 1D layout (R11 fallback) ----
    int Jlg = 4;
    size_t req = 0;
    size_t o_dstP, o_srcP, o_curD, o_curS, o_part, o_pio, o_h0sar, o_isi, o_Xsum;
    for (;; --Jlg) {
        int J = 1 << Jlg;
        size_t off = 0;
        auto A = [&](size_t bytes) { size_t o = off; off = (off + bytes + 127) & ~(size_t)127; return o; };
        o_dstP  = A((size_t)NB * CAP * 4);
        o_srcP  = A((size_t)NB * CAP * 2);
        o_curD  = A((size_t)NB * CSTR * 4);
        o_curS  = A((size_t)NB * CSTR * 4);
        o_part  = A((size_t)NB * J * BNODES * 4);
        o_pio   = A((size_t)Npad * 4);
        o_h0sar = A((size_t)Npad * 4);
        o_isi   = A((size_t)Npad * 4);
        o_Xsum  = A((size_t)G * 4);
        req = off;
        if (req <= ws_size || Jlg == 0) break;
    }

    bool fast = (N <= (1 << 19)) && (NB <= MAXNB) && (ws_size >= req) && (E >= 1);

    if (fast) {
        unsigned*       dstP = (unsigned*)(bp + o_dstP);
        unsigned short* srcP = (unsigned short*)(bp + o_srcP);
        unsigned* curD = (unsigned*)(bp + o_curD);
        unsigned* curS = (unsigned*)(bp + o_curS);
        unsigned* pDeg = (unsigned*)(bp + o_part);
        float*    pC   = (float*)(bp + o_part);
        float*    pT   = (float*)(bp + o_part);
        float* pio  = (float*)(bp + o_pio);
        float* h0s  = (float*)(bp + o_h0sar);
        float* sarr = (float*)(bp + o_h0sar);
        float* isiA = (float*)(bp + o_isi);
        float* Xsum = (float*)(bp + o_Xsum);

        int gridNp = (Npad + TB - 1) / TB;
        int gridN  = (N + TB - 1) / TB;
        int J = 1 << Jlg;
        int gridI = ((NB > G ? NB : G) + TB - 1) / TB;
        int NCH1 = (NCH + 1) / 2;
        int NCH2 = NCH - NCH1;

        init_kernel<<<gridI, TB, 0, stream>>>(curD, curS, nullptr, Xsum, NB, CAP, 0, 0, G);
        scatter_sort_kernel<<<NCH1, STB, 0, stream>>>(src, dst, curD, curS, dstP, srcP, NB, E, 0);
        if (NCH2 > 0)
            scatter_sort_kernel<<<NCH2, STB, 0, stream>>>(src, dst, curD, curS, dstP, srcP, NB, E, NCH1);
        deghist_kernel<<<NB * J, DTB, 0, stream>>>(srcP, dstP, curS, curD, CAP, pDeg, Jlg);
        prep_kernel<<<gridNp, TB, 0, stream>>>(pDeg, pio, h0s, isiA, Jlg, Npad);
        wh_kernel<0><<<NB * J, DTB, 0, stream>>>(dstP, curD, CAP, h0s, pC, Jlg);
        mid_kernel<<<gridNp, TB, 0, stream>>>(pC, pio, sarr, Jlg, Npad);
        wh_kernel<1><<<NB * J, DTB, 0, stream>>>(dstP, curD, CAP, sarr, pT, Jlg);
        poolfinal_kernel<<<gridN, TB, 0, stream>>>(pT, isiA, graph_ids, Xsum, Jlg, N);
        final_kernel<<<(out_size + TB - 1) / TB, TB, 0, stream>>>(Xsum, graph_ids,
                                                                  W1, W2, Wlast, out, N, out_size);
    } else {
        float* ws = (float*)d_ws;
        size_t f = 0;
        auto FA = [&](size_t n) { size_t o = f; f += (n + 3) & ~(size_t)3; return o; };
        size_t f_degin  = FA(N);
        size_t f_degout = FA(N);
        size_t f_agg1   = FA(N);
        size_t f_t2     = FA(N);
        size_t f_Xsum   = FA(G);
        size_t f_cnt    = FA(G);
        size_t zf = f;
        size_t f_isi = FA(N);
        size_t f_iso = FA(N);
        size_t f_h0s = FA(N);
        size_t f_s   = FA(N);
        hipMemsetAsync(ws, 0, zf * sizeof(float), stream);
        int gridE = (E + TB - 1) / TB;
        int gridN = (N + TB - 1) / TB;
        int gridO = (out_size + TB - 1) / TB;
        fb_deg_kernel<<<gridE, TB, 0, stream>>>(src, dst, ws + f_degout, ws + f_degin, E);
        fb_prep_kernel<<<gridN, TB, 0, stream>>>(ws + f_degin, ws + f_degout,
                                                 ws + f_isi, ws + f_iso, ws + f_h0s, N);
        fb_conv_kernel<<<gridE, TB, 0, stream>>>(src, dst, ws + f_h0s, ws + f_agg1, E);
        fb_mid_kernel<<<gridN, TB, 0, stream>>>(ws + f_agg1, ws + f_isi, ws + f_iso, ws + f_s, N);
        fb_conv_kernel<<<gridE, TB, 0, stream>>>(src, dst, ws + f_s, ws + f_t2, E);
        fb_pool_kernel<<<gridN, TB, 0, stream>>>(ws + f_t2, ws + f_isi, graph_ids,
                                                 ws + f_Xsum, ws + f_cnt, N);
        fb_final_kernel<<<gridO, TB, 0, stream>>>(ws + f_Xsum, ws + f_cnt, W1, W2, Wlast,
                                                  out, out_size);
    }
}